// Round 13
// baseline (58.635 us; speedup 1.0000x reference)
//
#include <hip/hip_runtime.h>

// SelfAttention (lambda attention) on MI355X.
// B=8, C=256, H=W=32, n=1024, DK=64, HEADS=4, DQ=256, DV=64. SF = 64^-0.25
#define SFC 0.35355339059327373f

typedef __attribute__((ext_vector_type(8))) short short8;
typedef __attribute__((ext_vector_type(16))) float f32x16;
typedef unsigned short ushort_t;

__device__ __forceinline__ float4 ld4(const float* p) { return *reinterpret_cast<const float4*>(p); }
__device__ __forceinline__ void st4(float* p, float4 v) { *reinterpret_cast<float4*>(p) = v; }

union F4 { float4 v; float f[4]; };
union S8 { short8 v; ushort_t u[8]; };

__device__ __forceinline__ ushort_t bfb(float f) {
  union { float f; unsigned u; } a; a.f = f;
  unsigned r = a.u + 0x7FFFu + ((a.u >> 16) & 1u);   // RNE f32->bf16
  return (ushort_t)(r >> 16);
}
__device__ __forceinline__ float bf2f(ushort_t u) {
  union { unsigned u; float f; } a; a.u = (unsigned)u << 16; return a.f;
}

__device__ __forceinline__ void gl16(const void* g, void* l) {
  __builtin_amdgcn_global_load_lds(
      (const __attribute__((address_space(1))) unsigned int*)g,
      (__attribute__((address_space(3))) unsigned int*)l, 16, 0, 0);
}

// ---------------------------------------------------------------------------
// K1: projection GEMM via MFMA, reading W and x f32 DIRECTLY (no prep pass).
//   At: W rows converted inline (pad 72). Bt: x transpose-staged via LDS
//   (pad 80, ds_write_b128). Outputs:
//   bm<4 (q rows): QB fragment-major bf16 (LDS-staged, coalesced store)
//   bm==4 (k rows): Pk f32 [64][8192]
//   bm==5 (v rows): VB2 fragment-major bf16 (LDS-staged, coalesced store)
//   bm<5: per-wave column-sum partials PSUM/PSQ[o][128] (non-atomic)
// ---------------------------------------------------------------------------
__global__ __launch_bounds__(256) void k_projm(
    const float* __restrict__ wq, const float* __restrict__ wk,
    const float* __restrict__ wv, const float* __restrict__ x,
    float* __restrict__ Pk, ushort_t* __restrict__ QB,
    ushort_t* __restrict__ VB2, float* __restrict__ PSUM,
    float* __restrict__ PSQ)
{
  __shared__ ushort_t SM[14848];      // At 64*72 | Bt 128*80 ; reused as STG
  ushort_t* At = SM;
  ushort_t* Bt = SM + 4608;
  const int t = threadIdx.x;
  const int bm = blockIdx.x, bn = blockIdx.y;
  const int o0 = bm * 64, col0 = bn * 128;
  const int b_img = bn >> 3, n0 = (bn & 7) * 128;
  const int w = t >> 6, l = t & 63, ln = l & 31, hi = l >> 5;
  const int wm = w & 1, wn = w >> 1;

  const float* wsrc = (bm < 4) ? (wq + (size_t)o0 * 256)
                    : (bm == 4) ? wk : wv;

  f32x16 acc0, acc1;
#pragma unroll
  for (int i = 0; i < 16; ++i) { acc0[i] = 0.f; acc1[i] = 0.f; }

  for (int k0 = 0; k0 < 256; k0 += 64) {
    __syncthreads();
    // ---- At from W f32 ----
#pragma unroll
    for (int i = 0; i < 2; ++i) {
      const int c = t + i * 256, row = c >> 3, k8 = (c & 7) * 8;
      const float* wr = wsrc + (size_t)row * 256 + k0 + k8;
      float4 a = ld4(wr), b2 = ld4(wr + 4);
      S8 s;
      s.u[0] = bfb(a.x); s.u[1] = bfb(a.y); s.u[2] = bfb(a.z); s.u[3] = bfb(a.w);
      s.u[4] = bfb(b2.x); s.u[5] = bfb(b2.y); s.u[6] = bfb(b2.z); s.u[7] = bfb(b2.w);
      *(short8*)(At + row * 72 + k8) = s.v;
    }
    // ---- Bt from x f32 (transpose-stage): n = nn+32*jj, c = cg*8+ci ----
    {
      const int nn = t & 31, cg = t >> 5;
      const float* xc = x + (size_t)b_img * 262144
                        + (size_t)(k0 + cg * 8) * 1024 + n0 + nn;
#pragma unroll
      for (int jj = 0; jj < 4; ++jj) {
        S8 s;
#pragma unroll
        for (int ci = 0; ci < 8; ++ci)
          s.u[ci] = bfb(xc[(size_t)ci * 1024 + 32 * jj]);
        *(short8*)(Bt + (nn + 32 * jj) * 80 + cg * 8) = s.v;
      }
    }
    __syncthreads();
    const ushort_t* ka  = At + (wm * 32 + ln) * 72 + hi * 8;
    const ushort_t* kb0 = Bt + (wn * 64 + ln) * 80 + hi * 8;
    const ushort_t* kb1 = Bt + (wn * 64 + 32 + ln) * 80 + hi * 8;
#pragma unroll
    for (int kc = 0; kc < 4; ++kc) {
      short8 a = *(const short8*)(ka + kc * 16);
      acc0 = __builtin_amdgcn_mfma_f32_32x32x16_bf16(a, *(const short8*)(kb0 + kc * 16), acc0, 0, 0, 0);
      acc1 = __builtin_amdgcn_mfma_f32_32x32x16_bf16(a, *(const short8*)(kb1 + kc * 16), acc1, 0, 0, 0);
    }
  }

  if (bm == 5) {
    // ---- VB2: stage in LDS, coalesced store ----
    __syncthreads();
    {
      const int n0l = wn * 64 + ln;
#pragma unroll
      for (int r = 0; r < 16; ++r) {
        const int v = wm * 32 + (r & 3) + 8 * (r >> 2) + 4 * hi;
#pragma unroll
        for (int half = 0; half < 2; ++half) {
          const int nl = n0l + half * 32;
          const int i2l = nl >> 5, j2 = nl & 31;
          const float val = half ? acc1[r] : acc0[r];
          SM[((i2l * 4 + wm * 2 + (j2 >> 4)) << 9)
             + ((v & 31) + 32 * ((j2 >> 3) & 1)) * 8 + (j2 & 7)] = bfb(val);
        }
      }
    }
    __syncthreads();
    {
      const int b2 = bn >> 3, i2b0 = (bn & 7) * 4;
      const int slot = t >> 4, off = (t & 15) * 32;
      const int i2l = slot >> 2, sub = slot & 3;
      ushort_t* gdst = VB2 + ((size_t)((b2 * 32 + i2b0 + i2l) * 4 + sub)) * 512 + off;
      const ushort_t* lsrc = SM + slot * 512 + off;
#pragma unroll
      for (int c = 0; c < 4; ++c)
        *(short8*)(gdst + c * 8) = *(const short8*)(lsrc + c * 8);
    }
  } else if (bm == 4) {
    // k rows -> Pk f32 (coalesced already)
#pragma unroll
    for (int r = 0; r < 16; ++r) {
      const int o = o0 + wm * 32 + (r & 3) + 8 * (r >> 2) + 4 * hi;  // 256..319
      float* dst = Pk + (size_t)(o - 256) * 8192 + col0 + wn * 64 + ln;
      dst[0]  = acc0[r];
      dst[32] = acc1[r];
    }
    // BN partials
#pragma unroll
    for (int r = 0; r < 16; ++r) {
      float s1 = acc0[r] + acc1[r];
      float s2 = acc0[r] * acc0[r] + acc1[r] * acc1[r];
#pragma unroll
      for (int off = 1; off < 32; off <<= 1) {
        s1 += __shfl_xor(s1, off, 64);
        s2 += __shfl_xor(s2, off, 64);
      }
      if (ln == 0) {
        const int o = o0 + wm * 32 + (r & 3) + 8 * (r >> 2) + 4 * hi;
        PSUM[o * 128 + bn * 2 + wn] = s1;
        PSQ [o * 128 + bn * 2 + wn] = s2;
      }
    }
  } else {
    // BN partials (regs only) first
#pragma unroll
    for (int r = 0; r < 16; ++r) {
      float s1 = acc0[r] + acc1[r];
      float s2 = acc0[r] * acc0[r] + acc1[r] * acc1[r];
#pragma unroll
      for (int off = 1; off < 32; off <<= 1) {
        s1 += __shfl_xor(s1, off, 64);
        s2 += __shfl_xor(s2, off, 64);
      }
      if (ln == 0) {
        const int o = o0 + wm * 32 + (r & 3) + 8 * (r >> 2) + 4 * hi;
        PSUM[o * 128 + bn * 2 + wn] = s1;
        PSQ [o * 128 + bn * 2 + wn] = s2;
      }
    }
    // ---- QB: stage in LDS, coalesced store ----
    __syncthreads();
    {
      const int kcq = 2 * wm;
#pragma unroll
      for (int r = 0; r < 16; ++r) {
        const int kc = kcq + ((r >> 3) & 1);
        const int lq = ln + 32 * ((r >> 2) & 1);
        const int iq = (r & 3) + 4 * hi;
#pragma unroll
        for (int half = 0; half < 2; ++half) {
          const int i1l = wn * 2 + half;
          const float val = half ? acc1[r] : acc0[r];
          SM[((i1l * 4 + kc) << 9) + lq * 8 + iq] = bfb(val);
        }
      }
    }
    __syncthreads();
    {
      const int b0 = col0 >> 10, i1b = (col0 >> 5) & 31;
      const int slot = t >> 4, off = (t & 15) * 32;
      const int i1l = slot >> 2, kc2 = slot & 3;
      ushort_t* gdst = QB + (((size_t)(b0 * 32 + i1b + i1l) * 4 + bm) * 4 + kc2) * 512 + off;
      const ushort_t* lsrc = SM + slot * 512 + off;
#pragma unroll
      for (int c = 0; c < 4; ++c)
        *(short8*)(gdst + c * 8) = *(const short8*)(lsrc + c * 8);
    }
  }
}

// ---------------------------------------------------------------------------
// K2: grid 768.
// blocks 0..511 (b, kc): inline BN finalize + softmax over n + FUSED content
//   context: ctx[b][kc][v] = sum_n ks[n]*V[v][n] -> CTXB bf16 [b][v][72].
// blocks 512..767: rpe -> RPEB2 conversion (one slot/thread) + finalize
//   q-channel SCALE/SHIFT from partials.
// ---------------------------------------------------------------------------
__global__ __launch_bounds__(256) void k_softctx(
    const float* __restrict__ Pk, const float* __restrict__ PSUM,
    const float* __restrict__ PSQ, const float* __restrict__ gq,
    const float* __restrict__ bq, const float* __restrict__ gk,
    const float* __restrict__ bk, const float* __restrict__ rpe,
    float* __restrict__ SCALE, float* __restrict__ SHIFT,
    const ushort_t* __restrict__ VB2, ushort_t* __restrict__ RPEB2,
    ushort_t* __restrict__ CTXB)
{
  __shared__ float red[8];
  __shared__ float scsh[2];
  __shared__ float cpart[4][64];
  const int t = threadIdx.x;

  if (blockIdx.x >= 512) {
    const int virt = blockIdx.x - 512;   // 0..255
    // ---- rpe -> RPEB2 fragment-major bf16 (folded k_prep) ----
    {
      const int slot = virt * 256 + t;   // 63 slices x 512 slots = 32256
      if (slot < 32256) {
        const int di = slot >> 9, s2 = slot & 511;
        const int tkc = s2 >> 6, l2 = s2 & 63, lnp = l2 & 31, hip = l2 >> 5;
        const int dj = (tkc >> 2) * 32 + lnp;
        const int k = (tkc & 3) * 16 + hip * 8;
        S8 o;
        if (dj < 63) {
          const float* s = rpe + (size_t)di * 4032 + dj * 64 + k;
          float4 a = ld4(s), b2 = ld4(s + 4);
          o.u[0] = bfb(a.x); o.u[1] = bfb(a.y); o.u[2] = bfb(a.z); o.u[3] = bfb(a.w);
          o.u[4] = bfb(b2.x); o.u[5] = bfb(b2.y); o.u[6] = bfb(b2.z); o.u[7] = bfb(b2.w);
        } else {
#pragma unroll
          for (int i = 0; i < 8; ++i) o.u[i] = 0;
        }
        *(short8*)(RPEB2 + (size_t)di * 4096 + tkc * 512 + l2 * 8) = o.v;
      }
    }
    // ---- q-channel SCALE/SHIFT ----
    const int ch = virt;                 // 0..255
    float s1 = 0.f, s2 = 0.f;
    if (t < 128) { s1 = PSUM[ch * 128 + t]; s2 = PSQ[ch * 128 + t]; }
#pragma unroll
    for (int off = 1; off < 64; off <<= 1) {
      s1 += __shfl_xor(s1, off, 64);
      s2 += __shfl_xor(s2, off, 64);
    }
    if ((t & 63) == 0) { red[t >> 6] = s1; red[4 + (t >> 6)] = s2; }
    __syncthreads();
    if (t == 0) {
      s1 = red[0] + red[1] + red[2] + red[3];
      s2 = red[4] + red[5] + red[6] + red[7];
      const float mu = s1 * (1.0f / 8192.0f);
      const float var = s2 * (1.0f / 8192.0f) - mu * mu;
      const float sc = rsqrtf(var + 1e-5f) * gq[ch] * SFC;
      SCALE[ch] = sc;
      SHIFT[ch] = bq[ch] * SFC - mu * sc;
    }
    return;
  }

  const int b = blockIdx.x >> 6, kc = blockIdx.x & 63;
  {
    const int ch = 256 + kc;
    float s1 = 0.f, s2 = 0.f;
    if (t < 128) { s1 = PSUM[ch * 128 + t]; s2 = PSQ[ch * 128 + t]; }
#pragma unroll
    for (int off = 1; off < 64; off <<= 1) {
      s1 += __shfl_xor(s1, off, 64);
      s2 += __shfl_xor(s2, off, 64);
    }
    if ((t & 63) == 0) { red[t >> 6] = s1; red[4 + (t >> 6)] = s2; }
    __syncthreads();
    if (t == 0) {
      s1 = red[0] + red[1] + red[2] + red[3];
      s2 = red[4] + red[5] + red[6] + red[7];
      const float mu = s1 * (1.0f / 8192.0f);
      const float var = s2 * (1.0f / 8192.0f) - mu * mu;
      const float sc = rsqrtf(var + 1e-5f) * gk[kc] * SFC;
      scsh[0] = sc;
      scsh[1] = bk[kc] * SFC - mu * sc;
    }
    __syncthreads();
  }
  const float sc = scsh[0], sh = scsh[1];

  const float4* rowp = (const float4*)(Pk + (size_t)kc * 8192 + b * 1024);
  float4 pv = rowp[t];
  float y0 = pv.x * sc + sh, y1 = pv.y * sc + sh;
  float y2 = pv.z * sc + sh, y3 = pv.w * sc + sh;
  float m = fmaxf(fmaxf(y0, y1), fmaxf(y2, y3));
#pragma unroll
  for (int off = 32; off; off >>= 1) m = fmaxf(m, __shfl_xor(m, off, 64));
  __shared__ float red2[8];
  const int w = t >> 6, l = t & 63;
  if (l == 0) red2[w] = m;
  __syncthreads();
  m = fmaxf(fmaxf(red2[0], red2[1]), fmaxf(red2[2], red2[3]));
  const float e0 = __expf(y0 - m), e1 = __expf(y1 - m);
  const float e2 = __expf(y2 - m), e3 = __expf(y3 - m);
  float su = e0 + e1 + e2 + e3;
#pragma unroll
  for (int off = 32; off; off >>= 1) su += __shfl_xor(su, off, 64);
  if (l == 0) red2[4 + w] = su;
  __syncthreads();
  const float inv = 1.0f / (red2[4] + red2[5] + red2[6] + red2[7]);
  const float k0v = e0 * inv, k1v = e1 * inv, k2v = e2 * inv, k3v = e3 * inv;

  // ---- fused content context ----
  const int n0 = t * 4;
  const int i2 = n0 >> 5;
  const int cX = (n0 >> 4) & 1, hi2 = (n0 >> 3) & 1, i0 = n0 & 7;
  const ushort_t* vbL = VB2 + (((size_t)(b * 32 + i2) * 2 + 0) * 2 + cX) * 512
                        + (32 * hi2) * 8 + i0;
  const ushort_t* vbH = vbL + 1024;
  float a64[64];
#pragma unroll
  for (int v = 0; v < 32; ++v) {
    ushort4 u = *(const ushort4*)(vbL + v * 8);
    a64[v] = k0v * bf2f(u.x) + k1v * bf2f(u.y) + k2v * bf2f(u.z) + k3v * bf2f(u.w);
  }
#pragma unroll
  for (int v = 0; v < 32; ++v) {
    ushort4 u = *(const ushort4*)(vbH + v * 8);
    a64[32 + v] = k0v * bf2f(u.x) + k1v * bf2f(u.y) + k2v * bf2f(u.z) + k3v * bf2f(u.w);
  }
  float c32[32];
#pragma unroll
  for (int j = 0; j < 32; ++j) {
    const float mine = (l & 32) ? a64[j + 32] : a64[j];
    const float send = (l & 32) ? a64[j] : a64[j + 32];
    c32[j] = mine + __shfl_xor(send, 32, 64);
  }
  float c16[16];
#pragma unroll
  for (int j = 0; j < 16; ++j) {
    const float mine = (l & 16) ? c32[j + 16] : c32[j];
    const float send = (l & 16) ? c32[j] : c32[j + 16];
    c16[j] = mine + __shfl_xor(send, 16, 64);
  }
  float c8[8];
#pragma unroll
  for (int j = 0; j < 8; ++j) {
    const float mine = (l & 8) ? c16[j + 8] : c16[j];
    const float send = (l & 8) ? c16[j] : c16[j + 8];
    c8[j] = mine + __shfl_xor(send, 8, 64);
  }
  float c4[4];
#pragma unroll
  for (int j = 0; j < 4; ++j) {
    const float mine = (l & 4) ? c8[j + 4] : c8[j];
    const float send = (l & 4) ? c8[j] : c8[j + 4];
    c4[j] = mine + __shfl_xor(send, 4, 64);
  }
  float c2[2];
#pragma unroll
  for (int j = 0; j < 2; ++j) {
    const float mine = (l & 2) ? c4[j + 2] : c4[j];
    const float send = (l & 2) ? c4[j] : c4[j + 2];
    c2[j] = mine + __shfl_xor(send, 2, 64);
  }
  {
    const float mine = (l & 1) ? c2[1] : c2[0];
    const float send = (l & 1) ? c2[0] : c2[1];
    cpart[w][l] = mine + __shfl_xor(send, 1, 64);
  }
  __syncthreads();
  if (w == 0) {
    const float s = cpart[0][l] + cpart[1][l] + cpart[2][l] + cpart[3][l];
    CTXB[(size_t)b * 4608 + l * 72 + kc] = bfb(s);
  }
}

// ---------------------------------------------------------------------------
// K3: positional lambda, block = (b, i1), grid 256, 8 waves (head m, group g).
// Unchanged from round 12: single rpe buffer, V loaded at use,
// __launch_bounds__(512,4), barrier-free loop, fused one-write shear.
// ---------------------------------------------------------------------------
extern __shared__ char ldsc[];

__global__ __launch_bounds__(512, 4) void k_pos(
    const ushort_t* __restrict__ QB, const ushort_t* __restrict__ RPEB2,
    const ushort_t* __restrict__ VB2, const float* __restrict__ SCALE,
    const float* __restrict__ SHIFT, const ushort_t* __restrict__ CTXB,
    float* __restrict__ out)
{
  float* out_l = (float*)ldsc;                 // [256][33] f32 = 33792
  ushort_t* SlB = (ushort_t*)(ldsc + 33792);   // 8 waves x [32][40] = 20480
  char* CtxL = ldsc + 54272;                   // 9216 (ctx^T [v][72] bf16)
                                               // total 63488

  const int t = threadIdx.x;
  const int b = blockIdx.x >> 5, i1 = blockIdx.x & 31;
  const int w = t >> 6, l = t & 63, ln = l & 31, hi = l >> 5;
  const int m = w & 3, g = w >> 2;

  // ---- issue ctx staging now; consumed after the post-loop barrier ----
  {
    const char* cs = (const char*)CTXB + (size_t)b * 9216;
    gl16(cs + w * 1024 + l * 16, CtxL + w * 1024 + l * 16);
    if (w == 0) gl16(cs + 8192 + l * 16, CtxL + 8192 + l * 16);
  }

  const ushort_t* rbase = RPEB2 + (size_t)(g * 16 - i1 + 31) * 4096;
  const ushort_t* vbase = VB2 + (size_t)(b * 32 + g * 16) * 2048;

  // prologue prefetch: rpe frags for s=0 (single buffer)
  short8 rA[8];
#pragma unroll
  for (int f = 0; f < 8; ++f) rA[f] = *(const short8*)(rbase + f * 512 + l * 8);

  // ---- q fragments reg-direct + in-register BN scale ----
  short8 qf[4];
  {
    const ushort_t* qb = QB + (((size_t)(b * 32 + i1) * 4 + m) * 4) * 512 + l * 8;
#pragma unroll
    for (int kc = 0; kc < 4; ++kc) {
      S8 raw; raw.v = *(const short8*)(qb + kc * 512);
      const int chb = m * 64 + kc * 16 + hi * 8;
      F4 s0, s1, h0, h1;
      s0.v = ld4(SCALE + chb); s1.v = ld4(SCALE + chb + 4);
      h0.v = ld4(SHIFT + chb); h1.v = ld4(SHIFT + chb + 4);
      S8 o;
#pragma unroll
      for (int i = 0; i < 8; ++i) {
        const float f = bf2f(raw.u[i]);
        const float scv = (i < 4) ? s0.f[i] : s1.f[i - 4];
        const float shv = (i < 4) ? h0.f[i] : h1.f[i - 4];
        o.u[i] = bfb(f * scv + shv);
      }
      qf[kc] = o.v;
    }
  }

  f32x16 sv0, sv1;
#pragma unroll
  for (int i = 0; i < 16; ++i) { sv0[i] = 0.f; sv1[i] = 0.f; }

  ushort_t* sm = SlB + w * 1280;               // private S tile [32 j1][40]

  for (int s = 0; s < 16; ++s) {
    // T-GEMM: both dj-tiles from rA
    f32x16 t0, t1;
#pragma unroll
    for (int i = 0; i < 16; ++i) { t0[i] = 0.f; t1[i] = 0.f; }
#pragma unroll
    for (int kc = 0; kc < 4; ++kc) {
      t0 = __builtin_amdgcn_mfma_f32_32x32x16_bf16(qf[kc], rA[kc],     t0, 0, 0, 0);
      t1 = __builtin_amdgcn_mfma_f32_32x32x16_bf16(qf[kc], rA[4 + kc], t1, 0, 0, 0);
    }
    // rA dead: prefetch next slice now (overlaps shear + SV)
    if (s + 1 < 16) {
      const ushort_t* rn = rbase + (size_t)(s + 1) * 4096;
#pragma unroll
      for (int f = 0; f < 8; ++f) rA[f] = *(const short8*)(rn + f * 512 + l * 8);
    }
    // fused shear: exactly one of {j2a, j2a+32} in [0,32) -> one write per reg
#pragma unroll
    for (int r = 0; r < 16; ++r) {
      const int j1 = (r & 3) + 8 * (r >> 2) + 4 * hi;
      const int j2a = ln + j1 - 31;
      const bool useA = (j2a >= 0);
      const int j2 = useA ? j2a : (j2a + 32);
      sm[j1 * 40 + j2] = bfb(useA ? t0[r] : t1[r]);
    }
    // SV: V fragments loaded in pairs at their consuming MFMAs
    const ushort_t* sa = sm + ln * 40 + hi * 8;
    short8 sA0 = *(const short8*)(sa);
    short8 sA1 = *(const short8*)(sa + 16);
    const ushort_t* vp = vbase + (size_t)s * 2048 + l * 8;
    {
      short8 v00 = *(const short8*)(vp);
      short8 v01 = *(const short8*)(vp + 512);
      sv0 = __builtin_amdgcn_mfma_f32_32x32x16_bf16(sA0, v00, sv0, 0, 0, 0);
      sv0 = __builtin_amdgcn_mfma_f32_32x32x16_bf16(sA1, v01, sv0, 0, 0, 0);
    }
    {
      short8 v10 = *(const short8*)(vp + 1024);
      short8 v11 = *(const short8*)(vp + 1536);
      sv1 = __builtin_amdgcn_mfma_f32_32x32x16_bf16(sA0, v10, sv1, 0, 0, 0);
      sv1 = __builtin_amdgcn_mfma_f32_32x32x16_bf16(sA1, v11, sv1, 0, 0, 0);
    }
  }

  __syncthreads();   // loop done; drains ctx gl16; SlB dead

  if (g == 0) {
    const ushort_t* cb = (const ushort_t*)CtxL;
    const ushort_t* c0 = cb + ln * 72 + hi * 8;
    const ushort_t* c1 = cb + (32 + ln) * 72 + hi * 8;
#pragma unroll
    for (int kc = 0; kc < 4; ++kc) {
      sv0 = __builtin_amdgcn_mfma_f32_32x32x16_bf16(qf[kc], *(const short8*)(c0 + kc * 16), sv0, 0, 0, 0);
      sv1 = __builtin_amdgcn_mfma_f32_32x32x16_bf16(qf[kc], *(const short8*)(c1 + kc * 16), sv1, 0, 0, 0);
    }
  } else {
#pragma unroll
    for (int r = 0; r < 16; ++r) {
      const int j1 = (r & 3) + 8 * (r >> 2) + 4 * hi;
      out_l[(m * 64 + ln) * 33 + j1]      = sv0[r];
      out_l[(m * 64 + 32 + ln) * 33 + j1] = sv1[r];
    }
  }
  __syncthreads();
  if (g == 0) {
#pragma unroll
    for (int r = 0; r < 16; ++r) {
      const int j1 = (r & 3) + 8 * (r >> 2) + 4 * hi;
      out_l[(m * 64 + ln) * 33 + j1]      += sv0[r];
      out_l[(m * 64 + 32 + ln) * 33 + j1] += sv1[r];
    }
  }
  __syncthreads();
  {
    const int ch = t >> 1, jh = (t & 1) * 16;
    float* dst = out + (size_t)b * 262144 + (size_t)ch * 1024 + i1 * 32 + jh;
    const float* srow = out_l + ch * 33 + jh;
#pragma unroll
    for (int gq2 = 0; gq2 < 4; ++gq2)
      st4(dst + gq2 * 4, make_float4(srow[gq2 * 4], srow[gq2 * 4 + 1],
                                     srow[gq2 * 4 + 2], srow[gq2 * 4 + 3]));
  }
}

// ---------------------------------------------------------------------------
extern "C" void kernel_launch(void* const* d_in, const int* in_sizes, int n_in,
                              void* d_out, int out_size, void* d_ws, size_t ws_size,
                              hipStream_t stream) {
  const float* x   = (const float*)d_in[0];
  const float* wq  = (const float*)d_in[1];
  const float* gq  = (const float*)d_in[2];
  const float* bq  = (const float*)d_in[3];
  const float* wk  = (const float*)d_in[4];
  const float* gk  = (const float*)d_in[5];
  const float* bk  = (const float*)d_in[6];
  const float* wv  = (const float*)d_in[7];
  const float* rpe = (const float*)d_in[8];
  float* out = (float*)d_out;
  char* W = (char*)d_ws;

  float* Pk       = (float*)W;                       //  2,097,152 B
  ushort_t* QB    = (ushort_t*)(W + 2097152);        //  4,194,304
  float* PSUM     = (float*)(W + 6291456);           //    163,840
  float* PSQ      = (float*)(W + 6455296);           //    163,840
  float* SCALE    = (float*)(W + 6619136);           //      2,048
  float* SHIFT    = (float*)(W + 6621184);           //      2,048
  ushort_t* CTXB  = (ushort_t*)(W + 6623232);        //     73,728
  ushort_t* RPEB2 = (ushort_t*)(W + 6696960);        //    516,096
  ushort_t* VB2   = (ushort_t*)(W + 7213056);        //  1,048,576

  k_projm<<<dim3(6, 64), 256, 0, stream>>>(wq, wk, wv, x, Pk, QB, VB2, PSUM, PSQ);
  k_softctx<<<768, 256, 0, stream>>>(Pk, PSUM, PSQ, gq, bq, gk, bk, rpe,
                                     SCALE, SHIFT, VB2, RPEB2, CTXB);

  hipFuncSetAttribute((const void*)k_pos,
                      hipFuncAttributeMaxDynamicSharedMemorySize, 63488);
  k_pos<<<256, 512, 63488, stream>>>(QB, RPEB2, VB2, SCALE, SHIFT, CTXB, out);
}

// Round 14
// 56.642 us; speedup vs baseline: 1.0352x; 1.0352x over previous
//
#include <hip/hip_runtime.h>

// SelfAttention (lambda attention) on MI355X.
// B=8, C=256, H=W=32, n=1024, DK=64, HEADS=4, DQ=256, DV=64. SF = 64^-0.25
#define SFC 0.35355339059327373f

typedef __attribute__((ext_vector_type(8))) short short8;
typedef __attribute__((ext_vector_type(16))) float f32x16;
typedef unsigned short ushort_t;

__device__ __forceinline__ float4 ld4(const float* p) { return *reinterpret_cast<const float4*>(p); }
__device__ __forceinline__ void st4(float* p, float4 v) { *reinterpret_cast<float4*>(p) = v; }

union F4 { float4 v; float f[4]; };
union S8 { short8 v; ushort_t u[8]; };

__device__ __forceinline__ ushort_t bfb(float f) {
  union { float f; unsigned u; } a; a.f = f;
  unsigned r = a.u + 0x7FFFu + ((a.u >> 16) & 1u);   // RNE f32->bf16
  return (ushort_t)(r >> 16);
}
__device__ __forceinline__ float bf2f(ushort_t u) {
  union { unsigned u; float f; } a; a.u = (unsigned)u << 16; return a.f;
}

__device__ __forceinline__ void gl16(const void* g, void* l) {
  __builtin_amdgcn_global_load_lds(
      (const __attribute__((address_space(1))) unsigned int*)g,
      (__attribute__((address_space(3))) unsigned int*)l, 16, 0, 0);
}

// ---------------------------------------------------------------------------
// K0: prep.
// blocks 0..62:  rpe -> RPEB2 fragment-major bf16 [di][tkc][lane][8]
// blocks 63..110: Wq/Wk/Wv -> WB bf16 [384][256]
// blocks 111..1134: x -> XBT bf16 [b*1024+n][256 c]
// ---------------------------------------------------------------------------
__global__ __launch_bounds__(256) void k_prep(
    const float* __restrict__ rpe, const float* __restrict__ wq,
    const float* __restrict__ wk, const float* __restrict__ wv,
    const float* __restrict__ x, ushort_t* __restrict__ RPEB2,
    ushort_t* __restrict__ WB, ushort_t* __restrict__ XBT)
{
  const int bx = blockIdx.x, t = threadIdx.x;
  if (bx < 63) {
    const int di = bx;
#pragma unroll
    for (int it = 0; it < 2; ++it) {
      const int slot = t + it * 256;           // 0..511
      const int tkc = slot >> 6;               // tau*4 + kc
      const int l = slot & 63, lnp = l & 31, hip = l >> 5;
      const int dj = (tkc >> 2) * 32 + lnp;
      const int k = (tkc & 3) * 16 + hip * 8;
      S8 o;
      if (dj < 63) {
        const float* s = rpe + (size_t)di * 4032 + dj * 64 + k;
        float4 a = ld4(s), b = ld4(s + 4);
        o.u[0] = bfb(a.x); o.u[1] = bfb(a.y); o.u[2] = bfb(a.z); o.u[3] = bfb(a.w);
        o.u[4] = bfb(b.x); o.u[5] = bfb(b.y); o.u[6] = bfb(b.z); o.u[7] = bfb(b.w);
      } else {
#pragma unroll
        for (int i = 0; i < 8; ++i) o.u[i] = 0;
      }
      *(short8*)(RPEB2 + (size_t)di * 4096 + tkc * 512 + l * 8) = o.v;
    }
  } else if (bx < 111) {
    const int cc = (bx - 63) * 256 + t;        // 0..12287
    const int o = cc >> 5, k8 = (cc & 31) * 8;
    const float* src = (o < 256) ? (wq + o * 256)
                      : (o < 320) ? (wk + (o - 256) * 256)
                                  : (wv + (o - 320) * 256);
    float4 a = ld4(src + k8), b = ld4(src + k8 + 4);
    S8 s;
    s.u[0] = bfb(a.x); s.u[1] = bfb(a.y); s.u[2] = bfb(a.z); s.u[3] = bfb(a.w);
    s.u[4] = bfb(b.x); s.u[5] = bfb(b.y); s.u[6] = bfb(b.z); s.u[7] = bfb(b.w);
    *(short8*)(WB + (size_t)o * 256 + k8) = s.v;
  } else {
    const int id = (bx - 111) * 256 + t;       // 0..262143
    const int ng = id & 8191, c8 = id >> 13;   // n global, c chunk
    const int bb = ng >> 10, nn = ng & 1023;
    const float* src = x + (size_t)bb * 262144 + (size_t)(c8 * 8) * 1024 + nn;
    S8 s;
#pragma unroll
    for (int j = 0; j < 8; ++j) s.u[j] = bfb(src[(size_t)j * 1024]);
    *(short8*)(XBT + (size_t)ng * 256 + c8 * 8) = s.v;
  }
}

// ---------------------------------------------------------------------------
// K1: projection GEMM via MFMA. Outputs:
//   bm<4 (q rows): QB fragment-major bf16 (LDS-staged, coalesced store)
//   bm==4 (k rows): Pk f32 [64][8192]
//   bm==5 (v rows): VB2 fragment-major bf16 (LDS-staged, coalesced store)
//   bm<5: per-wave column-sum partials PSUM/PSQ[o][128] (non-atomic)
// ---------------------------------------------------------------------------
__global__ __launch_bounds__(256) void k_projm(
    const ushort_t* __restrict__ WB, const ushort_t* __restrict__ XBT,
    float* __restrict__ Pk, ushort_t* __restrict__ QB,
    ushort_t* __restrict__ VB2, float* __restrict__ PSUM,
    float* __restrict__ PSQ)
{
  __shared__ ushort_t SM[13824];      // At 64*72 | Bt 128*72 ; reused as STG
  ushort_t* At = SM;
  ushort_t* Bt = SM + 4608;
  const int t = threadIdx.x;
  const int bm = blockIdx.x, bn = blockIdx.y;
  const int o0 = bm * 64, col0 = bn * 128;
  const int w = t >> 6, l = t & 63, ln = l & 31, hi = l >> 5;
  const int wm = w & 1, wn = w >> 1;

  f32x16 acc0, acc1;
#pragma unroll
  for (int i = 0; i < 16; ++i) { acc0[i] = 0.f; acc1[i] = 0.f; }

  for (int k0 = 0; k0 < 256; k0 += 64) {
    __syncthreads();
#pragma unroll
    for (int i = 0; i < 2; ++i) {
      const int c = t + i * 256, row = c >> 3, k8 = (c & 7) * 8;
      *(short8*)(At + row * 72 + k8) =
          *(const short8*)(WB + (size_t)(o0 + row) * 256 + k0 + k8);
    }
#pragma unroll
    for (int i = 0; i < 4; ++i) {
      const int c = t + i * 256, row = c >> 3, k8 = (c & 7) * 8;
      *(short8*)(Bt + row * 72 + k8) =
          *(const short8*)(XBT + (size_t)(col0 + row) * 256 + k0 + k8);
    }
    __syncthreads();
    const ushort_t* ka  = At + (wm * 32 + ln) * 72 + hi * 8;
    const ushort_t* kb0 = Bt + (wn * 64 + ln) * 72 + hi * 8;
    const ushort_t* kb1 = Bt + (wn * 64 + 32 + ln) * 72 + hi * 8;
#pragma unroll
    for (int kc = 0; kc < 4; ++kc) {
      short8 a = *(const short8*)(ka + kc * 16);
      acc0 = __builtin_amdgcn_mfma_f32_32x32x16_bf16(a, *(const short8*)(kb0 + kc * 16), acc0, 0, 0, 0);
      acc1 = __builtin_amdgcn_mfma_f32_32x32x16_bf16(a, *(const short8*)(kb1 + kc * 16), acc1, 0, 0, 0);
    }
  }

  if (bm == 5) {
    // ---- VB2: stage in LDS, coalesced store ----
    __syncthreads();
    {
      const int n0l = wn * 64 + ln;
#pragma unroll
      for (int r = 0; r < 16; ++r) {
        const int v = wm * 32 + (r & 3) + 8 * (r >> 2) + 4 * hi;
#pragma unroll
        for (int half = 0; half < 2; ++half) {
          const int nl = n0l + half * 32;
          const int i2l = nl >> 5, j2 = nl & 31;
          const float val = half ? acc1[r] : acc0[r];
          SM[((i2l * 4 + wm * 2 + (j2 >> 4)) << 9)
             + ((v & 31) + 32 * ((j2 >> 3) & 1)) * 8 + (j2 & 7)] = bfb(val);
        }
      }
    }
    __syncthreads();
    {
      const int b2 = bn >> 3, i2b0 = (bn & 7) * 4;
      const int slot = t >> 4, off = (t & 15) * 32;
      const int i2l = slot >> 2, sub = slot & 3;
      ushort_t* gdst = VB2 + ((size_t)((b2 * 32 + i2b0 + i2l) * 4 + sub)) * 512 + off;
      const ushort_t* lsrc = SM + slot * 512 + off;
#pragma unroll
      for (int c = 0; c < 4; ++c)
        *(short8*)(gdst + c * 8) = *(const short8*)(lsrc + c * 8);
    }
  } else if (bm == 4) {
    // k rows -> Pk f32 (coalesced already)
#pragma unroll
    for (int r = 0; r < 16; ++r) {
      const int o = o0 + wm * 32 + (r & 3) + 8 * (r >> 2) + 4 * hi;  // 256..319
      float* dst = Pk + (size_t)(o - 256) * 8192 + col0 + wn * 64 + ln;
      dst[0]  = acc0[r];
      dst[32] = acc1[r];
    }
    // BN partials
#pragma unroll
    for (int r = 0; r < 16; ++r) {
      float s1 = acc0[r] + acc1[r];
      float s2 = acc0[r] * acc0[r] + acc1[r] * acc1[r];
#pragma unroll
      for (int off = 1; off < 32; off <<= 1) {
        s1 += __shfl_xor(s1, off, 64);
        s2 += __shfl_xor(s2, off, 64);
      }
      if (ln == 0) {
        const int o = o0 + wm * 32 + (r & 3) + 8 * (r >> 2) + 4 * hi;
        PSUM[o * 128 + bn * 2 + wn] = s1;
        PSQ [o * 128 + bn * 2 + wn] = s2;
      }
    }
  } else {
    // BN partials (regs only) first
#pragma unroll
    for (int r = 0; r < 16; ++r) {
      float s1 = acc0[r] + acc1[r];
      float s2 = acc0[r] * acc0[r] + acc1[r] * acc1[r];
#pragma unroll
      for (int off = 1; off < 32; off <<= 1) {
        s1 += __shfl_xor(s1, off, 64);
        s2 += __shfl_xor(s2, off, 64);
      }
      if (ln == 0) {
        const int o = o0 + wm * 32 + (r & 3) + 8 * (r >> 2) + 4 * hi;
        PSUM[o * 128 + bn * 2 + wn] = s1;
        PSQ [o * 128 + bn * 2 + wn] = s2;
      }
    }
    // ---- QB: stage in LDS, coalesced store ----
    __syncthreads();
    {
      const int kcq = 2 * wm;
#pragma unroll
      for (int r = 0; r < 16; ++r) {
        const int kc = kcq + ((r >> 3) & 1);
        const int lq = ln + 32 * ((r >> 2) & 1);
        const int iq = (r & 3) + 4 * hi;
#pragma unroll
        for (int half = 0; half < 2; ++half) {
          const int i1l = wn * 2 + half;
          const float val = half ? acc1[r] : acc0[r];
          SM[((i1l * 4 + kc) << 9) + lq * 8 + iq] = bfb(val);
        }
      }
    }
    __syncthreads();
    {
      const int b0 = col0 >> 10, i1b = (col0 >> 5) & 31;
      const int slot = t >> 4, off = (t & 15) * 32;
      const int i1l = slot >> 2, kc2 = slot & 3;
      ushort_t* gdst = QB + (((size_t)(b0 * 32 + i1b + i1l) * 4 + bm) * 4 + kc2) * 512 + off;
      const ushort_t* lsrc = SM + slot * 512 + off;
#pragma unroll
      for (int c = 0; c < 4; ++c)
        *(short8*)(gdst + c * 8) = *(const short8*)(lsrc + c * 8);
    }
  }
}

// ---------------------------------------------------------------------------
// K2: grid 768.
// blocks 0..511 (b, kc): inline BN finalize + softmax over n + FUSED content
//   context: ctx[b][kc][v] = sum_n ks[n]*V[v][n] -> CTXB bf16 [b][v][72].
// blocks 512..767: finalize q-channel SCALE/SHIFT from partials.
// ---------------------------------------------------------------------------
__global__ __launch_bounds__(256) void k_softctx(
    const float* __restrict__ Pk, const float* __restrict__ PSUM,
    const float* __restrict__ PSQ, const float* __restrict__ gq,
    const float* __restrict__ bq, const float* __restrict__ gk,
    const float* __restrict__ bk, float* __restrict__ SCALE,
    float* __restrict__ SHIFT, const ushort_t* __restrict__ VB2,
    ushort_t* __restrict__ CTXB)
{
  __shared__ float red[8];
  __shared__ float scsh[2];
  __shared__ float cpart[4][64];
  const int t = threadIdx.x;

  if (blockIdx.x >= 512) {
    const int ch = blockIdx.x - 512;     // q channel 0..255
    float s1 = 0.f, s2 = 0.f;
    if (t < 128) { s1 = PSUM[ch * 128 + t]; s2 = PSQ[ch * 128 + t]; }
#pragma unroll
    for (int off = 1; off < 64; off <<= 1) {
      s1 += __shfl_xor(s1, off, 64);
      s2 += __shfl_xor(s2, off, 64);
    }
    if ((t & 63) == 0) { red[t >> 6] = s1; red[4 + (t >> 6)] = s2; }
    __syncthreads();
    if (t == 0) {
      s1 = red[0] + red[1] + red[2] + red[3];
      s2 = red[4] + red[5] + red[6] + red[7];
      const float mu = s1 * (1.0f / 8192.0f);
      const float var = s2 * (1.0f / 8192.0f) - mu * mu;
      const float sc = rsqrtf(var + 1e-5f) * gq[ch] * SFC;
      SCALE[ch] = sc;
      SHIFT[ch] = bq[ch] * SFC - mu * sc;
    }
    return;
  }

  const int b = blockIdx.x >> 6, kc = blockIdx.x & 63;
  {
    const int ch = 256 + kc;
    float s1 = 0.f, s2 = 0.f;
    if (t < 128) { s1 = PSUM[ch * 128 + t]; s2 = PSQ[ch * 128 + t]; }
#pragma unroll
    for (int off = 1; off < 64; off <<= 1) {
      s1 += __shfl_xor(s1, off, 64);
      s2 += __shfl_xor(s2, off, 64);
    }
    if ((t & 63) == 0) { red[t >> 6] = s1; red[4 + (t >> 6)] = s2; }
    __syncthreads();
    if (t == 0) {
      s1 = red[0] + red[1] + red[2] + red[3];
      s2 = red[4] + red[5] + red[6] + red[7];
      const float mu = s1 * (1.0f / 8192.0f);
      const float var = s2 * (1.0f / 8192.0f) - mu * mu;
      const float sc = rsqrtf(var + 1e-5f) * gk[kc] * SFC;
      scsh[0] = sc;
      scsh[1] = bk[kc] * SFC - mu * sc;
    }
    __syncthreads();
  }
  const float sc = scsh[0], sh = scsh[1];

  const float4* rowp = (const float4*)(Pk + (size_t)kc * 8192 + b * 1024);
  float4 pv = rowp[t];
  float y0 = pv.x * sc + sh, y1 = pv.y * sc + sh;
  float y2 = pv.z * sc + sh, y3 = pv.w * sc + sh;
  float m = fmaxf(fmaxf(y0, y1), fmaxf(y2, y3));
#pragma unroll
  for (int off = 32; off; off >>= 1) m = fmaxf(m, __shfl_xor(m, off, 64));
  __shared__ float red2[8];
  const int w = t >> 6, l = t & 63;
  if (l == 0) red2[w] = m;
  __syncthreads();
  m = fmaxf(fmaxf(red2[0], red2[1]), fmaxf(red2[2], red2[3]));
  const float e0 = __expf(y0 - m), e1 = __expf(y1 - m);
  const float e2 = __expf(y2 - m), e3 = __expf(y3 - m);
  float su = e0 + e1 + e2 + e3;
#pragma unroll
  for (int off = 32; off; off >>= 1) su += __shfl_xor(su, off, 64);
  if (l == 0) red2[4 + w] = su;
  __syncthreads();
  const float inv = 1.0f / (red2[4] + red2[5] + red2[6] + red2[7]);
  const float k0v = e0 * inv, k1v = e1 * inv, k2v = e2 * inv, k3v = e3 * inv;

  // ---- fused content context ----
  const int n0 = t * 4;
  const int i2 = n0 >> 5;
  const int cX = (n0 >> 4) & 1, hi2 = (n0 >> 3) & 1, i0 = n0 & 7;
  const ushort_t* vbL = VB2 + (((size_t)(b * 32 + i2) * 2 + 0) * 2 + cX) * 512
                        + (32 * hi2) * 8 + i0;
  const ushort_t* vbH = vbL + 1024;
  float a64[64];
#pragma unroll
  for (int v = 0; v < 32; ++v) {
    ushort4 u = *(const ushort4*)(vbL + v * 8);
    a64[v] = k0v * bf2f(u.x) + k1v * bf2f(u.y) + k2v * bf2f(u.z) + k3v * bf2f(u.w);
  }
#pragma unroll
  for (int v = 0; v < 32; ++v) {
    ushort4 u = *(const ushort4*)(vbH + v * 8);
    a64[32 + v] = k0v * bf2f(u.x) + k1v * bf2f(u.y) + k2v * bf2f(u.z) + k3v * bf2f(u.w);
  }
  float c32[32];
#pragma unroll
  for (int j = 0; j < 32; ++j) {
    const float mine = (l & 32) ? a64[j + 32] : a64[j];
    const float send = (l & 32) ? a64[j] : a64[j + 32];
    c32[j] = mine + __shfl_xor(send, 32, 64);
  }
  float c16[16];
#pragma unroll
  for (int j = 0; j < 16; ++j) {
    const float mine = (l & 16) ? c32[j + 16] : c32[j];
    const float send = (l & 16) ? c32[j] : c32[j + 16];
    c16[j] = mine + __shfl_xor(send, 16, 64);
  }
  float c8[8];
#pragma unroll
  for (int j = 0; j < 8; ++j) {
    const float mine = (l & 8) ? c16[j + 8] : c16[j];
    const float send = (l & 8) ? c16[j] : c16[j + 8];
    c8[j] = mine + __shfl_xor(send, 8, 64);
  }
  float c4[4];
#pragma unroll
  for (int j = 0; j < 4; ++j) {
    const float mine = (l & 4) ? c8[j + 4] : c8[j];
    const float send = (l & 4) ? c8[j] : c8[j + 4];
    c4[j] = mine + __shfl_xor(send, 4, 64);
  }
  float c2[2];
#pragma unroll
  for (int j = 0; j < 2; ++j) {
    const float mine = (l & 2) ? c4[j + 2] : c4[j];
    const float send = (l & 2) ? c4[j] : c4[j + 2];
    c2[j] = mine + __shfl_xor(send, 2, 64);
  }
  {
    const float mine = (l & 1) ? c2[1] : c2[0];
    const float send = (l & 1) ? c2[0] : c2[1];
    cpart[w][l] = mine + __shfl_xor(send, 1, 64);
  }
  __syncthreads();
  if (w == 0) {
    const float s = cpart[0][l] + cpart[1][l] + cpart[2][l] + cpart[3][l];
    CTXB[(size_t)b * 4608 + l * 72 + kc] = bfb(s);
  }
}

// ---------------------------------------------------------------------------
// K3: positional lambda, grid 512, block = (b, i1, head-pair hp).
// Each block owns disjoint output channels [hp*128, hp*128+128): no combine
// across blocks. 8 waves = 2 heads (h2) x 4 i2-groups (g, 8 i2 each).
// Per-wave body identical to round 12; 4-stage LDS combine; 46.6 KB LDS ->
// 2 blocks/CU at <=128 VGPR (true 4 waves/SIMD).
// ---------------------------------------------------------------------------
extern __shared__ char ldsc[];

__global__ __launch_bounds__(512, 4) void k_pos(
    const ushort_t* __restrict__ QB, const ushort_t* __restrict__ RPEB2,
    const ushort_t* __restrict__ VB2, const float* __restrict__ SCALE,
    const float* __restrict__ SHIFT, const ushort_t* __restrict__ CTXB,
    float* __restrict__ out)
{
  float* out_l = (float*)ldsc;                 // [128][33] f32 = 16896
  ushort_t* SlB = (ushort_t*)(ldsc + 16896);   // 8 waves x [32][40] = 20480
  char* CtxL = ldsc + 37376;                   // 9216 (ctx^T [v][72] bf16)
                                               // total 46592

  const int t = threadIdx.x;
  const int b = blockIdx.x >> 6;
  const int i1 = (blockIdx.x >> 1) & 31;
  const int hp = blockIdx.x & 1;
  const int w = t >> 6, l = t & 63, ln = l & 31, hi = l >> 5;
  const int h2 = w & 1, g = w >> 1;
  const int m = hp * 2 + h2;

  // ---- issue ctx staging now; consumed after the post-loop barrier ----
  {
    const char* cs = (const char*)CTXB + (size_t)b * 9216;
    gl16(cs + w * 1024 + l * 16, CtxL + w * 1024 + l * 16);
    if (w == 0) gl16(cs + 8192 + l * 16, CtxL + 8192 + l * 16);
  }

  const ushort_t* rbase = RPEB2 + (size_t)(g * 8 - i1 + 31) * 4096;
  const ushort_t* vbase = VB2 + (size_t)(b * 32 + g * 8) * 2048;

  // prologue prefetch: rpe frags for s=0 (single buffer)
  short8 rA[8];
#pragma unroll
  for (int f = 0; f < 8; ++f) rA[f] = *(const short8*)(rbase + f * 512 + l * 8);

  // ---- q fragments reg-direct + in-register BN scale ----
  short8 qf[4];
  {
    const ushort_t* qb = QB + (((size_t)(b * 32 + i1) * 4 + m) * 4) * 512 + l * 8;
#pragma unroll
    for (int kc = 0; kc < 4; ++kc) {
      S8 raw; raw.v = *(const short8*)(qb + kc * 512);
      const int chb = m * 64 + kc * 16 + hi * 8;
      F4 s0, s1, h0, h1;
      s0.v = ld4(SCALE + chb); s1.v = ld4(SCALE + chb + 4);
      h0.v = ld4(SHIFT + chb); h1.v = ld4(SHIFT + chb + 4);
      S8 o;
#pragma unroll
      for (int i = 0; i < 8; ++i) {
        const float f = bf2f(raw.u[i]);
        const float scv = (i < 4) ? s0.f[i] : s1.f[i - 4];
        const float shv = (i < 4) ? h0.f[i] : h1.f[i - 4];
        o.u[i] = bfb(f * scv + shv);
      }
      qf[kc] = o.v;
    }
  }

  f32x16 sv0, sv1;
#pragma unroll
  for (int i = 0; i < 16; ++i) { sv0[i] = 0.f; sv1[i] = 0.f; }

  ushort_t* sm = SlB + w * 1280;               // private S tile [32 j1][40]

  for (int s = 0; s < 8; ++s) {
    // T-GEMM: both dj-tiles from rA
    f32x16 t0, t1;
#pragma unroll
    for (int i = 0; i < 16; ++i) { t0[i] = 0.f; t1[i] = 0.f; }
#pragma unroll
    for (int kc = 0; kc < 4; ++kc) {
      t0 = __builtin_amdgcn_mfma_f32_32x32x16_bf16(qf[kc], rA[kc],     t0, 0, 0, 0);
      t1 = __builtin_amdgcn_mfma_f32_32x32x16_bf16(qf[kc], rA[4 + kc], t1, 0, 0, 0);
    }
    // rA dead: prefetch next slice now (overlaps shear + SV)
    if (s + 1 < 8) {
      const ushort_t* rn = rbase + (size_t)(s + 1) * 4096;
#pragma unroll
      for (int f = 0; f < 8; ++f) rA[f] = *(const short8*)(rn + f * 512 + l * 8);
    }
    // fused shear: exactly one of {j2a, j2a+32} in [0,32) -> one write per reg
#pragma unroll
    for (int r = 0; r < 16; ++r) {
      const int j1 = (r & 3) + 8 * (r >> 2) + 4 * hi;
      const int j2a = ln + j1 - 31;
      const bool useA = (j2a >= 0);
      const int j2 = useA ? j2a : (j2a + 32);
      sm[j1 * 40 + j2] = bfb(useA ? t0[r] : t1[r]);
    }
    // SV: V fragments loaded in pairs at their consuming MFMAs
    const ushort_t* sa = sm + ln * 40 + hi * 8;
    short8 sA0 = *(const short8*)(sa);
    short8 sA1 = *(const short8*)(sa + 16);
    const ushort_t* vp = vbase + (size_t)s * 2048 + l * 8;
    {
      short8 v00 = *(const short8*)(vp);
      short8 v01 = *(const short8*)(vp + 512);
      sv0 = __builtin_amdgcn_mfma_f32_32x32x16_bf16(sA0, v00, sv0, 0, 0, 0);
      sv0 = __builtin_amdgcn_mfma_f32_32x32x16_bf16(sA1, v01, sv0, 0, 0, 0);
    }
    {
      short8 v10 = *(const short8*)(vp + 1024);
      short8 v11 = *(const short8*)(vp + 1536);
      sv1 = __builtin_amdgcn_mfma_f32_32x32x16_bf16(sA0, v10, sv1, 0, 0, 0);
      sv1 = __builtin_amdgcn_mfma_f32_32x32x16_bf16(sA1, v11, sv1, 0, 0, 0);
    }
  }

  __syncthreads();   // loop done; drains ctx gl16; SlB dead

  // content epilogue folded into group 0's partials
  if (g == 0) {
    const ushort_t* cb = (const ushort_t*)CtxL;
    const ushort_t* c0 = cb + ln * 72 + hi * 8;
    const ushort_t* c1 = cb + (32 + ln) * 72 + hi * 8;
#pragma unroll
    for (int kc = 0; kc < 4; ++kc) {
      sv0 = __builtin_amdgcn_mfma_f32_32x32x16_bf16(qf[kc], *(const short8*)(c0 + kc * 16), sv0, 0, 0, 0);
      sv1 = __builtin_amdgcn_mfma_f32_32x32x16_bf16(qf[kc], *(const short8*)(c1 + kc * 16), sv1, 0, 0, 0);
    }
  }

  // ---- 4-stage combine: local channel = h2*64 + tau*32 + ln ----
  auto emit = [&](bool add) {
#pragma unroll
    for (int r = 0; r < 16; ++r) {
      const int j1 = (r & 3) + 8 * (r >> 2) + 4 * hi;
      float* p0 = &out_l[(h2 * 64 + ln) * 33 + j1];
      float* p1 = &out_l[(h2 * 64 + 32 + ln) * 33 + j1];
      if (add) { *p0 += sv0[r]; *p1 += sv1[r]; }
      else     { *p0 = sv0[r];  *p1 = sv1[r]; }
    }
  };
  if (g == 3) emit(false);
  __syncthreads();
  if (g == 2) emit(true);
  __syncthreads();
  if (g == 1) emit(true);
  __syncthreads();
  if (g == 0) emit(true);
  __syncthreads();

  // ---- coalesced store of this block's 128-channel slice ----
  {
    const int ch = t >> 2, jh = (t & 3) * 8;
    float* dst = out + (size_t)b * 262144 + (size_t)(hp * 128 + ch) * 1024
                 + i1 * 32 + jh;
    const float* srow = out_l + ch * 33 + jh;
    st4(dst,     make_float4(srow[0], srow[1], srow[2], srow[3]));
    st4(dst + 4, make_float4(srow[4], srow[5], srow[6], srow[7]));
  }
}

// ---------------------------------------------------------------------------
extern "C" void kernel_launch(void* const* d_in, const int* in_sizes, int n_in,
                              void* d_out, int out_size, void* d_ws, size_t ws_size,
                              hipStream_t stream) {
  const float* x   = (const float*)d_in[0];
  const float* wq  = (const float*)d_in[1];
  const float* gq  = (const float*)d_in[2];
  const float* bq  = (const float*)d_in[3];
  const float* wk  = (const float*)d_in[4];
  const float* gk  = (const float*)d_in[5];
  const float* bk  = (const float*)d_in[6];
  const float* wv  = (const float*)d_in[7];
  const float* rpe = (const float*)d_in[8];
  float* out = (float*)d_out;
  char* W = (char*)d_ws;

  float* Pk       = (float*)W;                       //  2,097,152 B
  ushort_t* QB    = (ushort_t*)(W + 2097152);        //  4,194,304
  float* PSUM     = (float*)(W + 6291456);           //    163,840
  float* PSQ      = (float*)(W + 6455296);           //    163,840
  float* SCALE    = (float*)(W + 6619136);           //      2,048
  float* SHIFT    = (float*)(W + 6621184);           //      2,048
  ushort_t* CTXB  = (ushort_t*)(W + 6623232);        //     73,728
  ushort_t* RPEB2 = (ushort_t*)(W + 6696960);        //    516,096
  ushort_t* VB2   = (ushort_t*)(W + 7213056);        //  1,048,576
  ushort_t* WB    = (ushort_t*)(W + 8261632);        //    196,608
  ushort_t* XBT   = (ushort_t*)(W + 8458240);        //  4,194,304

  k_prep<<<1135, 256, 0, stream>>>(rpe, wq, wk, wv, x, RPEB2, WB, XBT);
  k_projm<<<dim3(6, 64), 256, 0, stream>>>(WB, XBT, Pk, QB, VB2, PSUM, PSQ);
  k_softctx<<<768, 256, 0, stream>>>(Pk, PSUM, PSQ, gq, bq, gk, bk,
                                     SCALE, SHIFT, VB2, CTXB);

  hipFuncSetAttribute((const void*)k_pos,
                      hipFuncAttributeMaxDynamicSharedMemorySize, 46592);
  k_pos<<<512, 512, 46592, stream>>>(QB, RPEB2, VB2, SCALE, SHIFT, CTXB, out);
}